// Round 1
// baseline (1075.324 us; speedup 1.0000x reference)
//
#include <hip/hip_runtime.h>
#include <hip/hip_bf16.h>
#include <math.h>

#define MDIM 32768
#define NDIM 2048
#define KDIM 2048

typedef __attribute__((ext_vector_type(8))) short bf16x8;
typedef __attribute__((ext_vector_type(4))) float f32x4;

__device__ __forceinline__ unsigned short f2bf(float f) {
  unsigned int u = __float_as_uint(f);
  u += 0x7FFFu + ((u >> 16) & 1u);
  return (unsigned short)(u >> 16);
}
__device__ __forceinline__ float bf2f(unsigned short b) {
  return __uint_as_float(((unsigned int)b) << 16);
}

__device__ __forceinline__ void gll16(const void* g, void* l) {
  __builtin_amdgcn_global_load_lds((__attribute__((address_space(1))) void*)g,
                                   (__attribute__((address_space(3))) void*)l,
                                   16, 0, 0);
}

// ---------------- split x into bf16 hi/lo ----------------
__global__ void split_x_kernel(const float4* __restrict__ x, ushort4* __restrict__ xhi,
                               ushort4* __restrict__ xlo, int n4) {
  int stride = gridDim.x * blockDim.x;
  for (int i = blockIdx.x * blockDim.x + threadIdx.x; i < n4; i += stride) {
    float4 v = x[i];
    ushort4 h, l;
    h.x = f2bf(v.x); l.x = f2bf(v.x - bf2f(h.x));
    h.y = f2bf(v.y); l.y = f2bf(v.y - bf2f(h.y));
    h.z = f2bf(v.z); l.z = f2bf(v.z - bf2f(h.z));
    h.w = f2bf(v.w); l.w = f2bf(v.w - bf2f(h.w));
    xhi[i] = h; xlo[i] = l;
  }
}

// ---------------- transpose + split W1 -> WT (N x K) hi/lo ----------------
__global__ void split_wT_kernel(const float* __restrict__ w1, unsigned short* __restrict__ wthi,
                                unsigned short* __restrict__ wtlo) {
  __shared__ float tile[32][33];
  int bx = blockIdx.x, by = blockIdx.y;    // bx: h-tile, by: d-tile
  int tx = threadIdx.x, ty = threadIdx.y;  // (32, 8)
#pragma unroll
  for (int r = 0; r < 4; ++r) {
    int d = by * 32 + ty + r * 8;
    tile[ty + r * 8][tx] = w1[(size_t)d * NDIM + bx * 32 + tx];
  }
  __syncthreads();
#pragma unroll
  for (int r = 0; r < 4; ++r) {
    int h = bx * 32 + ty + r * 8;
    float v = tile[tx][ty + r * 8];   // = w1[(by*32+tx)*N + h]
    unsigned short hi = f2bf(v);
    unsigned short lo = f2bf(v - bf2f(hi));
    size_t o = (size_t)h * KDIM + by * 32 + tx;
    wthi[o] = hi; wtlo[o] = lo;
  }
}

// ---------------- fused GEMM: logits partials ----------------
// logits[m] = sum_n relu(sum_k x[m,k] W1[k,n] + b1[n]) * W2[n]
// 3-product bf16 split for fp32-grade accuracy. 128x128 tile, BK=64, 4 waves.
__global__ __launch_bounds__(256, 2) void gemm_fused(
    const unsigned short* __restrict__ xhi, const unsigned short* __restrict__ xlo,
    const unsigned short* __restrict__ wthi, const unsigned short* __restrict__ wtlo,
    const float* __restrict__ b1, const float* __restrict__ w2,
    float* __restrict__ part) {
  __shared__ short As_hi[128 * 64];
  __shared__ short As_lo[128 * 64];
  __shared__ short Bs_hi[128 * 64];
  __shared__ short Bs_lo[128 * 64];

  const int t = threadIdx.x;
  const int l = t & 63;
  const int w = t >> 6;
  const int wm = w >> 1, wn = w & 1;
  const int q = l >> 4, r16 = l & 15;
  const int bn = blockIdx.x, bm = blockIdx.y;
  const int m0 = bm * 128, n0 = bn * 128;

  f32x4 acc[4][4];
  f32x4 zero = {0.f, 0.f, 0.f, 0.f};
#pragma unroll
  for (int a = 0; a < 4; ++a)
#pragma unroll
    for (int b = 0; b < 4; ++b) acc[a][b] = zero;

  for (int kt = 0; kt < KDIM / 64; ++kt) {
    __syncthreads();
    const int k0 = kt * 64;
#pragma unroll
    for (int i = 0; i < 4; ++i) {
      int lin = (i << 8) + t;
      int row = lin >> 3;                 // 0..127
      int kbyte = (lin & 7) << 4;         // 0..112
      int ldsoff = (lin & ~63) << 4;      // wave-uniform LDS base (bytes)
      size_t abyte = ((size_t)(m0 + row) * KDIM + k0) * 2 + kbyte;
      size_t bbyte = ((size_t)(n0 + row) * KDIM + k0) * 2 + kbyte;
      gll16((const char*)xhi + abyte, (char*)As_hi + ldsoff);
      gll16((const char*)xlo + abyte, (char*)As_lo + ldsoff);
      gll16((const char*)wthi + bbyte, (char*)Bs_hi + ldsoff);
      gll16((const char*)wtlo + bbyte, (char*)Bs_lo + ldsoff);
    }
    __syncthreads();
#pragma unroll
    for (int kk = 0; kk < 2; ++kk) {
      bf16x8 ah[4], al[4], bh[4], bl[4];
      const int ko = kk * 32 + q * 8;
#pragma unroll
      for (int f = 0; f < 4; ++f) {
        ah[f] = *(const bf16x8*)&As_hi[(wm * 64 + f * 16 + r16) * 64 + ko];
        al[f] = *(const bf16x8*)&As_lo[(wm * 64 + f * 16 + r16) * 64 + ko];
        bh[f] = *(const bf16x8*)&Bs_hi[(wn * 64 + f * 16 + r16) * 64 + ko];
        bl[f] = *(const bf16x8*)&Bs_lo[(wn * 64 + f * 16 + r16) * 64 + ko];
      }
#pragma unroll
      for (int fm = 0; fm < 4; ++fm)
#pragma unroll
        for (int fn = 0; fn < 4; ++fn) {
          acc[fm][fn] = __builtin_amdgcn_mfma_f32_16x16x32_bf16(ah[fm], bh[fn], acc[fm][fn], 0, 0, 0);
          acc[fm][fn] = __builtin_amdgcn_mfma_f32_16x16x32_bf16(ah[fm], bl[fn], acc[fm][fn], 0, 0, 0);
          acc[fm][fn] = __builtin_amdgcn_mfma_f32_16x16x32_bf16(al[fm], bh[fn], acc[fm][fn], 0, 0, 0);
        }
    }
  }

  // epilogue: relu(acc + b1) * w2, reduce over columns
  float b1v[4], w2v[4];
#pragma unroll
  for (int fn = 0; fn < 4; ++fn) {
    int n = n0 + wn * 64 + fn * 16 + r16;
    b1v[fn] = b1[n];
    w2v[fn] = w2[n];
  }

  float val[4][4];
#pragma unroll
  for (int fm = 0; fm < 4; ++fm)
#pragma unroll
    for (int j = 0; j < 4; ++j) {
      float s = 0.f;
#pragma unroll
      for (int fn = 0; fn < 4; ++fn) {
        float h = acc[fm][fn][j] + b1v[fn];
        h = fmaxf(h, 0.f);
        s += h * w2v[fn];
      }
      // C/D layout: col = lane&15, row = (lane>>4)*4 + j  -> reduce over the 16 cols
      s += __shfl_xor(s, 1);
      s += __shfl_xor(s, 2);
      s += __shfl_xor(s, 4);
      s += __shfl_xor(s, 8);
      val[fm][j] = s;
    }

  __syncthreads();                 // done with LDS tiles, reuse as reduction buffer
  float* red = (float*)As_hi;      // 256 floats
  if (r16 == 0) {
#pragma unroll
    for (int fm = 0; fm < 4; ++fm)
#pragma unroll
      for (int j = 0; j < 4; ++j)
        red[wn * 128 + wm * 64 + fm * 16 + q * 4 + j] = val[fm][j];
  }
  __syncthreads();
  if (t < 128) {
    float p = red[t] + red[128 + t];
    part[(size_t)(m0 + t) * 16 + bn] = p;   // deterministic per-N-tile partial
  }
}

// ---------------- reduce partials -> logits ----------------
__global__ void reduce_part(const float* __restrict__ part, const float* __restrict__ b2,
                            float* __restrict__ logits) {
  int m = blockIdx.x * blockDim.x + threadIdx.x;
  if (m >= MDIM) return;
  float s = 0.f;
#pragma unroll
  for (int i = 0; i < 16; ++i) s += part[(size_t)m * 16 + i];
  logits[m] = s + b2[0];
}

// ---------------- per-batch-row: expected_k, top-k mask ----------------
__global__ void rowstats(const float* __restrict__ logits, float* __restrict__ mask_out,
                         float* __restrict__ ek_out) {
  __shared__ float vals[2048];
  __shared__ float srt[2048];
  __shared__ float redf[256];
  __shared__ int redi[256];
  int b = blockIdx.x, t = threadIdx.x;
  const float* row = logits + (size_t)b * 2048;
  float psum = 0.f;
  for (int i = t; i < 2048; i += 256) {
    float v = row[i];
    vals[i] = v; srt[i] = v;
    psum += 1.f / (1.f + expf(-v));
  }
  redf[t] = psum;
  __syncthreads();
  for (int s = 128; s > 0; s >>= 1) {
    if (t < s) redf[t] += redf[t + s];
    __syncthreads();
  }
  float ek = redf[0];
  int k = (int)ek;          // truncation toward zero, matches astype(int32)
  if (k < 32) k = 32;
  if (k > 2048) k = 2048;
  if (t == 0) ek_out[b] = ek;

  // bitonic sort ascending
  for (int ksz = 2; ksz <= 2048; ksz <<= 1) {
    for (int j = ksz >> 1; j > 0; j >>= 1) {
      for (int i = t; i < 2048; i += 256) {
        int ixj = i ^ j;
        if (ixj > i) {
          float a = srt[i], c = srt[ixj];
          bool up = ((i & ksz) == 0);
          if ((a > c) == up) { srt[i] = c; srt[ixj] = a; }
        }
      }
      __syncthreads();
    }
  }
  float thr = srt[2048 - k];   // k-th largest

  int cnt = 0;
  for (int i = t; i < 2048; i += 256) cnt += (vals[i] > thr) ? 1 : 0;
  redi[t] = cnt;
  __syncthreads();
  for (int s = 128; s > 0; s >>= 1) {
    if (t < s) redi[t] += redi[t + s];
    __syncthreads();
  }
  int n_gt = redi[0];
  int need = k - n_gt;   // #ties to admit, by smallest index (stable argsort)

  for (int i = t; i < 2048; i += 256) {
    float v = vals[i];
    float m = 0.f;
    if (v > thr) m = 1.f;
    else if (v == thr) {
      int pre = 0;
      for (int p = 0; p < i; ++p) pre += (vals[p] == thr) ? 1 : 0;
      if (pre < need) m = 1.f;
    }
    mask_out[(size_t)b * 2048 + i] = m;
  }
}

// ---------------- filtered = x * mask ----------------
__global__ void filter_k(const float4* __restrict__ x, const float* __restrict__ mask,
                         float4* __restrict__ out, int n4) {
  int stride = gridDim.x * blockDim.x;
  for (int i = blockIdx.x * blockDim.x + threadIdx.x; i < n4; i += stride) {
    float m = mask[i >> 9];   // 512 float4 per row (D=2048)
    float4 v = x[i];
    v.x *= m; v.y *= m; v.z *= m; v.w *= m;
    out[i] = v;
  }
}

extern "C" void kernel_launch(void* const* d_in, const int* in_sizes, int n_in,
                              void* d_out, int out_size, void* d_ws, size_t ws_size,
                              hipStream_t stream) {
  const float* x  = (const float*)d_in[0];   // [16,2048,2048]
  const float* w1 = (const float*)d_in[1];   // [2048,2048]
  const float* b1 = (const float*)d_in[2];   // [2048]
  const float* w2 = (const float*)d_in[3];   // [2048,1]
  const float* b2 = (const float*)d_in[4];   // [1]

  float* out_filt = (float*)d_out;                         // 67108864 floats
  float* out_mask = out_filt + (size_t)67108864;           // 32768
  float* out_ek   = out_mask + 32768;                      // 16

  // x_hi parked in out0 region (268 MB >= 134 MB), overwritten by filter at the end
  unsigned short* xhi = (unsigned short*)d_out;

  char* wsb = (char*)d_ws;
  unsigned short* xlo  = (unsigned short*)wsb;                      // 134217728 B
  unsigned short* wthi = (unsigned short*)(wsb + 134217728);        // 8388608 B
  unsigned short* wtlo = (unsigned short*)(wsb + 142606336);        // 8388608 B
  float* part   = (float*)(wsb + 150994944);                        // 2097152 B
  float* logits = (float*)(wsb + 153092096);                        // 131072 B

  split_x_kernel<<<dim3(4096), dim3(256), 0, stream>>>(
      (const float4*)x, (ushort4*)xhi, (ushort4*)xlo, 16777216);
  split_wT_kernel<<<dim3(64, 64), dim3(32, 8), 0, stream>>>(w1, wthi, wtlo);
  gemm_fused<<<dim3(16, 256), dim3(256), 0, stream>>>(
      xhi, xlo, wthi, wtlo, b1, w2, part);
  reduce_part<<<dim3(128), dim3(256), 0, stream>>>(part, b2, logits);
  rowstats<<<dim3(16), dim3(256), 0, stream>>>(logits, out_mask, out_ek);
  filter_k<<<dim3(4096), dim3(256), 0, stream>>>(
      (const float4*)x, out_mask, (float4*)out_filt, 16777216);
}